// Round 4
// baseline (218.418 us; speedup 1.0000x reference)
//
#include <hip/hip_runtime.h>
#include <hip/hip_bf16.h>

// ---------------------------------------------------------------------------
// PointNet Feature Propagation, MI355X (gfx950)
//   Algebraic restructure: y0 = upts@W0a^T + sum_j w_j * Z[idx_j],
//   Z = kpts@W0b^T  (interp commutes with the 1x1 conv).
//   K1a: chunked 3-NN scan (dot-form + med3 packed keys)
//   K1b: merge_w -> per-point idx/weights only (1 MB)
//   KZ:  zgemm  Z = bf16(kpts) @ W0b^T   [16384][256] bf16
//   K1c: gemm1c U-GEMM (K=128, single-stage) + LDS-staged Z combine + stats0
//   K4:  gemm2 (BN0 finalize inline, BN0+ReLU fused A)   -> y1
//   K6:  bn_out (BN1 finalize inline) -> out
// ---------------------------------------------------------------------------

typedef __attribute__((ext_vector_type(8))) short short8;
typedef __attribute__((ext_vector_type(4))) float f32x4;

#define BB 8
#define NN 8192
#define SS 2048
#define M_TOT (BB * NN)      // 65536 points
#define N1DIM 256
#define K2DIM 256
#define N2DIM 128
#define NCH 8
#define CHS (SS / NCH)
#define BK 64

#define KEY_MASK 0xFFFFF800u
#define IDX_MASK 0x7FFu

__device__ __forceinline__ unsigned short f2bf(float f) {
    unsigned int x = __float_as_uint(f);
    unsigned int r = x + 0x7fffu + ((x >> 16) & 1u);  // RNE
    return (unsigned short)(r >> 16);
}
__device__ __forceinline__ float bf2f(unsigned short u) {
    return __uint_as_float(((unsigned int)u) << 16);
}
__device__ __forceinline__ unsigned int med3_u32(unsigned int a, unsigned int b,
                                                 unsigned int c) {
    unsigned int r;
    asm("v_med3_u32 %0, %1, %2, %3" : "=v"(r) : "v"(a), "v"(b), "v"(c));
    return r;
}

// async 16B global->LDS DMA. LDS dest must be wave-uniform base + lane*16;
// global src is per-lane (pre-swizzled-source pattern).
__device__ __forceinline__ void gload_lds16(const void* g, void* lds) {
    __builtin_amdgcn_global_load_lds(
        (const __attribute__((address_space(1))) unsigned int*)g,
        (__attribute__((address_space(3))) unsigned int*)lds, 16, 0, 0);
}

// ---------------------------------------------------------------------------
// K1a: chunked 3-NN scan. 10 VALU/candidate, SGPR k-data.
// ---------------------------------------------------------------------------
__global__ __launch_bounds__(256) void nn_cand_kernel(
    const float* __restrict__ uxyz,
    const float4* __restrict__ kpack,   // [B][S] (x,y,z,|k|^2)
    unsigned int* __restrict__ cand)    // [NCH][3][M_TOT]
{
    const int tid  = threadIdx.x;
    const int bid  = blockIdx.x;
    const int ch   = bid & 7;
    const int tile = (bid >> 3) & 31;
    const int b    = bid >> 8;

    const int n = tile * 256 + tid;
    const float* up = uxyz + ((size_t)b * NN + n) * 3;
    const float ux = up[0], uy = up[1], uz = up[2];
    const float uu  = fmaf(ux, ux, fmaf(uy, uy, uz * uz));
    const float m2x = -2.0f * ux, m2y = -2.0f * uy, m2z = -2.0f * uz;

    const float4* kb = kpack + (size_t)b * SS + ch * CHS;
    const int base = ch * CHS;

    unsigned int k0 = 0xFFFFFFFFu, k1 = 0xFFFFFFFFu, k2 = 0xFFFFFFFFu;
#pragma unroll 8
    for (int s = 0; s < CHS; ++s) {
        float4 kc = kb[s];
        float d = kc.w + uu;
        d = fmaf(m2z, kc.z, d);
        d = fmaf(m2y, kc.y, d);
        d = fmaf(m2x, kc.x, d);
        d = fmaxf(d, 0.0f);
        unsigned int key = (__float_as_uint(d) & KEY_MASK) | (unsigned int)(base + s);
        unsigned int nk1 = med3_u32(k0, k1, key);
        unsigned int nk2 = med3_u32(k1, k2, key);
        k0 = min(k0, key);
        k1 = nk1;
        k2 = nk2;
    }

    const size_t pt = (size_t)b * NN + n;
    cand[(size_t)(ch * 3 + 0) * M_TOT + pt] = k0;
    cand[(size_t)(ch * 3 + 1) * M_TOT + pt] = k1;
    cand[(size_t)(ch * 3 + 2) * M_TOT + pt] = k2;
}

// ---------------------------------------------------------------------------
// K1b: merge 24 keys -> quantized top-6 -> exact rescue top-3 -> idx/weights.
// widx[pt] = {bits(w0), bits(w1), i0|(i1<<16), i2}; w2 = 1-w0-w1 downstream.
// ---------------------------------------------------------------------------
__global__ __launch_bounds__(256) void merge_w_kernel(
    const unsigned int* __restrict__ cand,
    const float4* __restrict__ kpack,
    const float* __restrict__ uxyz,
    uint4* __restrict__ widx)
{
    const size_t pt = (size_t)blockIdx.x * 256 + threadIdx.x;
    const int b = (int)(pt >> 13);

    unsigned int k[6];
#pragma unroll
    for (int i = 0; i < 6; ++i) k[i] = 0xFFFFFFFFu;
#pragma unroll
    for (int ch = 0; ch < NCH; ++ch) {
#pragma unroll
        for (int j = 0; j < 3; ++j) {
            unsigned int t = cand[(size_t)(ch * 3 + j) * M_TOT + pt];
#pragma unroll
            for (int i = 0; i < 6; ++i) {
                unsigned int a = min(k[i], t);
                t = max(k[i], t);
                k[i] = a;
            }
        }
    }

    const float* up = uxyz + pt * 3;
    const float ux = up[0], uy = up[1], uz = up[2];
    const float4* kpb4 = kpack + (size_t)b * SS;
    unsigned long long e[6];
#pragma unroll
    for (int i = 0; i < 6; ++i) {
        unsigned int idx = k[i] & IDX_MASK;
        float4 kc = kpb4[idx];
        float dx = kc.x - ux, dy = kc.y - uy, dz = kc.z - uz;
        float d = fmaf(dx, dx, fmaf(dy, dy, dz * dz));
        e[i] = ((unsigned long long)__float_as_uint(d) << 32) | idx;
    }
#pragma unroll
    for (int i = 0; i < 3; ++i)
#pragma unroll
        for (int j = i + 1; j < 6; ++j)
            if (e[j] < e[i]) { unsigned long long t = e[i]; e[i] = e[j]; e[j] = t; }

    float d0 = __uint_as_float((unsigned int)(e[0] >> 32));
    float d1 = __uint_as_float((unsigned int)(e[1] >> 32));
    float d2 = __uint_as_float((unsigned int)(e[2] >> 32));
    float r0 = 1.0f / (d0 + 1e-8f);
    float r1 = 1.0f / (d1 + 1e-8f);
    float r2 = 1.0f / (d2 + 1e-8f);
    float rs = 1.0f / (r0 + r1 + r2);
    unsigned int i0 = (unsigned int)(e[0] & IDX_MASK);
    unsigned int i1 = (unsigned int)(e[1] & IDX_MASK);
    unsigned int i2 = (unsigned int)(e[2] & IDX_MASK);
    widx[pt] = make_uint4(__float_as_uint(r0 * rs), __float_as_uint(r1 * rs),
                          i0 | (i1 << 16), i2);
}

// ---------------------------------------------------------------------------
// K0: split W0 -> Wa [256][128] / Wb [256][256] bf16; W1 bf16; kpack.
// ---------------------------------------------------------------------------
__global__ __launch_bounds__(256) void cvt_w_kernel(
    const float* __restrict__ W0, const float* __restrict__ W1,
    const float* __restrict__ kxyz,
    unsigned short* __restrict__ Wa, unsigned short* __restrict__ Wb,
    unsigned short* __restrict__ Wb1, float4* __restrict__ kpack)
{
    int i = blockIdx.x * 256 + threadIdx.x;
    if (i < 256 * 384) {
        int o = i / 384, c = i - o * 384;
        unsigned short v = f2bf(W0[i]);
        if (c < 128) Wa[o * 128 + c] = v;
        else         Wb[o * 256 + (c - 128)] = v;
    }
    if (i < N2DIM * K2DIM) Wb1[i] = f2bf(W1[i]);
    if (i < BB * SS) {
        const float* p = kxyz + (size_t)i * 3;
        float px = p[0], py = p[1], pz = p[2];
        kpack[i] = make_float4(px, py, pz, fmaf(px, px, fmaf(py, py, pz * pz)));
    }
}

// ---------------------------------------------------------------------------
// KZ: Z = bf16(kpts) @ Wb^T.  Tile 128x128 (N-split 2), BK=64, dbuf,
// A reg-staged f32->bf16, B global_load_lds, XOR swizzle. 64KB LDS.
// ---------------------------------------------------------------------------
__global__ __launch_bounds__(512, 4) void zgemm_kernel(
    const float* __restrict__ kpts,        // [16384][256] f32
    const unsigned short* __restrict__ Wb, // [256][256] bf16
    unsigned short* __restrict__ Z)        // [16384][256] bf16
{
    __shared__ __align__(128) unsigned char smem[2 * 32768];

    const int tid = threadIdx.x;
    const int l = tid & 63, w = tid >> 6;
    const int wm = w >> 2, wn = w & 3;
    const int mt = blockIdx.x >> 1, nh = blockIdx.x & 1;
    const int row0 = mt * 128;
    const int srow = l >> 3, sbo = (l & 7) * 16;
    const int lr = tid >> 2, lcq = tid & 3;

    f32x4 acc[4][2];
#pragma unroll
    for (int m = 0; m < 4; ++m)
#pragma unroll
        for (int n = 0; n < 2; ++n) {
            f32x4 z = {0.f, 0.f, 0.f, 0.f};
            acc[m][n] = z;
        }

    const unsigned char* Bb = (const unsigned char*)Wb + (size_t)nh * 128 * 512;
    float4 af0, af1, af2, af3;

    auto issueA = [&](int t) {
        const float* src = kpts + (size_t)(row0 + lr) * 256 + t * 64 + lcq * 16;
        af0 = ((const float4*)src)[0];
        af1 = ((const float4*)src)[1];
        af2 = ((const float4*)src)[2];
        af3 = ((const float4*)src)[3];
    };
    auto stageB = [&](int buf, int t) {
        unsigned char* Bl = smem + buf * 32768 + 16384;
#pragma unroll
        for (int i = 0; i < 2; ++i) {
            const int r = w * 16 + i * 8 + srow;
            gload_lds16(Bb + (size_t)r * 512 + t * 128 + (sbo ^ ((r & 7) << 4)),
                        Bl + r * 128 + sbo);
        }
    };
    auto xformA = [&](int buf) {
        unsigned char* Al = smem + buf * 32768;
        short8 o0, o1;
        o0[0] = (short)f2bf(af0.x); o0[1] = (short)f2bf(af0.y);
        o0[2] = (short)f2bf(af0.z); o0[3] = (short)f2bf(af0.w);
        o0[4] = (short)f2bf(af1.x); o0[5] = (short)f2bf(af1.y);
        o0[6] = (short)f2bf(af1.z); o0[7] = (short)f2bf(af1.w);
        o1[0] = (short)f2bf(af2.x); o1[1] = (short)f2bf(af2.y);
        o1[2] = (short)f2bf(af2.z); o1[3] = (short)f2bf(af2.w);
        o1[4] = (short)f2bf(af3.x); o1[5] = (short)f2bf(af3.y);
        o1[6] = (short)f2bf(af3.z); o1[7] = (short)f2bf(af3.w);
        const int bo = lcq * 32;
        *(short8*)(Al + lr * 128 + ((bo) ^ ((lr & 7) << 4))) = o0;
        *(short8*)(Al + lr * 128 + ((bo + 16) ^ ((lr & 7) << 4))) = o1;
    };
    auto compute = [&](int buf) {
        const unsigned char* Al = smem + buf * 32768;
        const unsigned char* Bl = Al + 16384;
#pragma unroll
        for (int ks = 0; ks < 2; ++ks) {
            const int bo = ks * 64 + (l >> 4) * 16;
            short8 a[4], bq[2];
#pragma unroll
            for (int m = 0; m < 4; ++m) {
                const int r = wm * 64 + m * 16 + (l & 15);
                a[m] = *(const short8*)(Al + r * 128 + (bo ^ ((r & 7) << 4)));
            }
#pragma unroll
            for (int n = 0; n < 2; ++n) {
                const int r = wn * 32 + n * 16 + (l & 15);
                bq[n] = *(const short8*)(Bl + r * 128 + (bo ^ ((r & 7) << 4)));
            }
#pragma unroll
            for (int m = 0; m < 4; ++m)
#pragma unroll
                for (int n = 0; n < 2; ++n)
                    acc[m][n] = __builtin_amdgcn_mfma_f32_16x16x32_bf16(
                        a[m], bq[n], acc[m][n], 0, 0, 0);
        }
    };

    issueA(0);
    stageB(0, 0);
    xformA(0);
    __syncthreads();
#pragma unroll
    for (int t = 0; t < 4; ++t) {
        const int cur = t & 1;
        if (t + 1 < 4) { issueA(t + 1); stageB(cur ^ 1, t + 1); }
        compute(cur);
        if (t + 1 < 4) xformA(cur ^ 1);
        __syncthreads();
    }

#pragma unroll
    for (int m = 0; m < 4; ++m) {
        const int row = row0 + wm * 64 + m * 16 + (l >> 4) * 4;
#pragma unroll
        for (int n = 0; n < 2; ++n) {
            const int col = nh * 128 + wn * 32 + n * 16 + (l & 15);
            f32x4 v = acc[m][n];
#pragma unroll
            for (int r = 0; r < 4; ++r)
                Z[(size_t)(row + r) * 256 + col] = f2bf(v[r]);
        }
    }
}

// ---------------------------------------------------------------------------
// K1c: y0 = upts@Wa^T + sum_j w_j Z[idx_j]; stats0.
// Tile 128x256, K=128 fully staged (A 32KB reg-cvt + B 64KB gload = 96KB),
// then LDS reused for two 64-point Z chunks (96KB each, gload gather).
// ---------------------------------------------------------------------------
__global__ __launch_bounds__(512, 2) void gemm1c_kernel(
    const float* __restrict__ upts,          // [M][128] f32
    const unsigned short* __restrict__ Wa,   // [256][128] bf16
    const unsigned short* __restrict__ Z,    // [16384][256] bf16
    const uint4* __restrict__ widx,          // [M]
    unsigned short* __restrict__ Y0,         // [M][256] bf16
    float* __restrict__ stats)               // [512]: sum|sumsq
{
    __shared__ __align__(128) unsigned char smem[98304];

    const int tid = threadIdx.x;
    const int l = tid & 63, w = tid >> 6;
    const int wm = w >> 2, wn = w & 3;
    const int row0 = blockIdx.x * 128;
    const int lr = tid >> 2, lcq = tid & 3;

    // ---- stage B: Wa 256 rows x 256B (gload, pre-swizzled source) ----
    {
        const unsigned char* Bb = (const unsigned char*)Wa;
#pragma unroll
        for (int i = 0; i < 8; ++i) {
            const int off = w * 8192 + i * 1024 + l * 16;
            const int r = off >> 8;
            const int inner = (l & 15) * 16;
            gload_lds16(Bb + r * 256 + (inner ^ ((r & 7) << 4)),
                        smem + 32768 + off);
        }
    }
    // ---- stage A: upts f32 -> bf16, swizzled ds_write (rows 256B) ----
    {
        const float* src = upts + (size_t)(row0 + lr) * 128 + lcq * 32;
        float4 f[8];
#pragma unroll
        for (int q = 0; q < 8; ++q) f[q] = ((const float4*)src)[q];
#pragma unroll
        for (int q = 0; q < 4; ++q) {
            float4 fa = f[q * 2], fb = f[q * 2 + 1];
            short8 o;
            o[0] = (short)f2bf(fa.x); o[1] = (short)f2bf(fa.y);
            o[2] = (short)f2bf(fa.z); o[3] = (short)f2bf(fa.w);
            o[4] = (short)f2bf(fb.x); o[5] = (short)f2bf(fb.y);
            o[6] = (short)f2bf(fb.z); o[7] = (short)f2bf(fb.w);
            *(short8*)(smem + lr * 256 +
                       ((lcq * 64 + q * 16) ^ ((lr & 7) << 4))) = o;
        }
    }
    __syncthreads();

    // ---- GEMM: K=128, 4 ks, 64 MFMA/wave ----
    f32x4 acc[4][4];
#pragma unroll
    for (int m = 0; m < 4; ++m)
#pragma unroll
        for (int n = 0; n < 4; ++n) {
            f32x4 z = {0.f, 0.f, 0.f, 0.f};
            acc[m][n] = z;
        }
#pragma unroll
    for (int ks = 0; ks < 4; ++ks) {
        const int bo = ks * 64 + (l >> 4) * 16;
        short8 a[4], bq[4];
#pragma unroll
        for (int m = 0; m < 4; ++m) {
            const int r = wm * 64 + m * 16 + (l & 15);
            a[m] = *(const short8*)(smem + r * 256 + (bo ^ ((r & 7) << 4)));
        }
#pragma unroll
        for (int n = 0; n < 4; ++n) {
            const int r = wn * 64 + n * 16 + (l & 15);
            bq[n] = *(const short8*)(smem + 32768 + r * 256 + (bo ^ ((r & 7) << 4)));
        }
#pragma unroll
        for (int m = 0; m < 4; ++m)
#pragma unroll
            for (int n = 0; n < 4; ++n)
                acc[m][n] = __builtin_amdgcn_mfma_f32_16x16x32_bf16(
                    a[m], bq[n], acc[m][n], 0, 0, 0);
    }
    __syncthreads();   // all LDS reads done; region reused for Z chunks

    // ---- combine: two chunks of 64 points (chunk c <-> waves wm==c) ----
    const int bb = row0 >> 13;
    const unsigned char* Zb = (const unsigned char*)Z + (size_t)bb * 2048 * 512;
    float s1[4] = {0.f, 0.f, 0.f, 0.f}, s2[4] = {0.f, 0.f, 0.f, 0.f};

    for (int c = 0; c < 2; ++c) {
        if (c) __syncthreads();              // chunk0 readers done
        // stage 192 Z rows (64 pts x 3), 512B each, pre-swizzled source
#pragma unroll
        for (int i = 0; i < 12; ++i) {
            const int rr = w * 24 + i * 2 + (l >> 5);
            const int p = rr / 3;
            const int j = rr - p * 3;
            const size_t pt = (size_t)row0 + c * 64 + p;
            uint4 wv = widx[pt];
            unsigned int idx = (j == 2) ? wv.w
                             : ((j == 1) ? (wv.z >> 16) : (wv.z & 0xFFFFu));
            gload_lds16(Zb + (size_t)idx * 512 + (((l & 31) * 16) ^ ((rr & 7) << 4)),
                        smem + (w * 24 + i * 2) * 512 + l * 16);
        }
        __syncthreads();                     // Z staged
        if (wm == c) {
#pragma unroll
            for (int m = 0; m < 4; ++m) {
#pragma unroll
                for (int r = 0; r < 4; ++r) {
                    const int p_loc = m * 16 + ((l >> 4) << 2) + r;
                    const size_t pt = (size_t)row0 + c * 64 + p_loc;
                    uint4 wv = widx[pt];
                    const float w0 = __uint_as_float(wv.x);
                    const float w1 = __uint_as_float(wv.y);
                    const float w2 = 1.0f - w0 - w1;
                    const int rb = p_loc * 3 * 512;
#pragma unroll
                    for (int n = 0; n < 4; ++n) {
                        const int col = wn * 64 + n * 16 + (l & 15);
                        const int cb = col * 2;
                        float z0 = bf2f(*(const unsigned short*)(
                            smem + rb + (cb ^ (((p_loc * 3) & 7) << 4))));
                        float z1 = bf2f(*(const unsigned short*)(
                            smem + rb + 512 + (cb ^ (((p_loc * 3 + 1) & 7) << 4))));
                        float z2 = bf2f(*(const unsigned short*)(
                            smem + rb + 1024 + (cb ^ (((p_loc * 3 + 2) & 7) << 4))));
                        float f = acc[m][n][r];
                        f = fmaf(w0, z0, f);
                        f = fmaf(w1, z1, f);
                        f = fmaf(w2, z2, f);
                        Y0[pt * 256 + col] = f2bf(f);
                        s1[n] += f;
                        s2[n] += f * f;
                    }
                }
            }
        }
    }

#pragma unroll
    for (int n = 0; n < 4; ++n) {
        s1[n] += __shfl_xor(s1[n], 16, 64);
        s1[n] += __shfl_xor(s1[n], 32, 64);
        s2[n] += __shfl_xor(s2[n], 16, 64);
        s2[n] += __shfl_xor(s2[n], 32, 64);
    }
    if (l < 16) {
#pragma unroll
        for (int n = 0; n < 4; ++n) {
            const int col = wn * 64 + n * 16 + l;
            atomicAdd(&stats[col], s1[n]);
            atomicAdd(&stats[N1DIM + col], s2[n]);
        }
    }
}

// ---------------------------------------------------------------------------
// K4: GEMM2  y1 = relu(bn0(y0)) @ W1^T  (unchanged from R3)
// ---------------------------------------------------------------------------
#define G2_NT (K2DIM / BK)   // 4
__global__ __launch_bounds__(512, 4) void gemm2_kernel(
    const unsigned short* __restrict__ Y0,
    const unsigned short* __restrict__ Wb,
    const float* __restrict__ stats0,
    const float* __restrict__ g0,
    const float* __restrict__ beta0,
    float* __restrict__ Y1,
    float* __restrict__ stats)
{
    __shared__ __align__(128) unsigned char smem[2 * 32768];
    __shared__ float sgm[K2DIM], sga[K2DIM];

    const int tid = threadIdx.x;
    const int l = tid & 63, w = tid >> 6;
    const int wm = w >> 2, wn = w & 3;
    const int row0 = blockIdx.x * 128;
    const int srow = l >> 3;
    const int sbo  = (l & 7) * 16;
    const int lr  = tid >> 2;
    const int lcq = tid & 3;

    f32x4 acc[4][2];
#pragma unroll
    for (int m = 0; m < 4; ++m)
#pragma unroll
        for (int n = 0; n < 2; ++n) {
            f32x4 z = {0.f, 0.f, 0.f, 0.f};
            acc[m][n] = z;
        }

    const unsigned char* Bb = (const unsigned char*)Wb;
    short8 areg0, areg1;

    auto issueA = [&](int t) {
        const unsigned short* src = Y0 + (size_t)(row0 + lr) * K2DIM + t * BK + lcq * 16;
        areg0 = *(const short8*)src;
        areg1 = *(const short8*)(src + 8);
    };
    auto stageB = [&](int buf, int t) {
        unsigned char* Bl = smem + buf * 32768 + 16384;
        const int k0b = t * (BK * 2);
#pragma unroll
        for (int i = 0; i < 2; ++i) {
            const int r = w * 16 + i * 8 + srow;
            gload_lds16(Bb + (size_t)r * (K2DIM * 2) + k0b + (sbo ^ ((r & 7) << 4)),
                        Bl + r * 128 + sbo);
        }
    };
    auto xformA = [&](int buf, int t) {
        unsigned char* Al = smem + buf * 32768;
        const int kb = t * BK + lcq * 16;
        short8 o0, o1;
#pragma unroll
        for (int j = 0; j < 8; ++j) {
            float f = bf2f((unsigned short)areg0[j]);
            f = fmaxf(fmaf(f, sgm[kb + j], sga[kb + j]), 0.f);
            o0[j] = (short)f2bf(f);
            float g = bf2f((unsigned short)areg1[j]);
            g = fmaxf(fmaf(g, sgm[kb + 8 + j], sga[kb + 8 + j]), 0.f);
            o1[j] = (short)f2bf(g);
        }
        const int bo = lcq * 32;
        *(short8*)(Al + lr * 128 + ((bo) ^ ((lr & 7) << 4))) = o0;
        *(short8*)(Al + lr * 128 + ((bo + 16) ^ ((lr & 7) << 4))) = o1;
    };
    auto compute = [&](int buf) {
        const unsigned char* Al = smem + buf * 32768;
        const unsigned char* Bl = Al + 16384;
#pragma unroll
        for (int ks = 0; ks < 2; ++ks) {
            const int bo = ks * 64 + (l >> 4) * 16;
            short8 a[4], bq[2];
#pragma unroll
            for (int m = 0; m < 4; ++m) {
                const int r = wm * 64 + m * 16 + (l & 15);
                a[m] = *(const short8*)(Al + r * 128 + (bo ^ ((r & 7) << 4)));
            }
#pragma unroll
            for (int n = 0; n < 2; ++n) {
                const int r = wn * 32 + n * 16 + (l & 15);
                bq[n] = *(const short8*)(Bl + r * 128 + (bo ^ ((r & 7) << 4)));
            }
#pragma unroll
            for (int m = 0; m < 4; ++m)
#pragma unroll
                for (int n = 0; n < 2; ++n)
                    acc[m][n] = __builtin_amdgcn_mfma_f32_16x16x32_bf16(
                        a[m], bq[n], acc[m][n], 0, 0, 0);
        }
    };

    if (tid < K2DIM) {
        const float inv = 1.0f / (float)M_TOT;
        float mean = stats0[tid] * inv;
        float var  = stats0[N1DIM + tid] * inv - mean * mean;
        float m = g0[tid] * rsqrtf(var + 1e-5f);
        sgm[tid] = m;
        sga[tid] = beta0[tid] - mean * m;
    }
    issueA(0);
    stageB(0, 0);
    __syncthreads();
    xformA(0, 0);
    __syncthreads();

#pragma unroll
    for (int t = 0; t < G2_NT; ++t) {
        const int cur = t & 1;
        if (t + 1 < G2_NT) { issueA(t + 1); stageB(cur ^ 1, t + 1); }
        compute(cur);
        if (t + 1 < G2_NT) xformA(cur ^ 1, t + 1);
        __syncthreads();
    }

    float s1[2] = {0.f, 0.f}, s2[2] = {0.f, 0.f};
#pragma unroll
    for (int m = 0; m < 4; ++m) {
        const int row = row0 + wm * 64 + m * 16 + (l >> 4) * 4;
#pragma unroll
        for (int n = 0; n < 2; ++n) {
            const int col = wn * 32 + n * 16 + (l & 15);
            f32x4 v = acc[m][n];
#pragma unroll
            for (int r = 0; r < 4; ++r) {
                float f = v[r];
                Y1[(size_t)(row + r) * N2DIM + col] = f;
                s1[n] += f;
                s2[n] += f * f;
            }
        }
    }
#pragma unroll
    for (int n = 0; n < 2; ++n) {
        s1[n] += __shfl_xor(s1[n], 16, 64);
        s1[n] += __shfl_xor(s1[n], 32, 64);
        s2[n] += __shfl_xor(s2[n], 16, 64);
        s2[n] += __shfl_xor(s2[n], 32, 64);
    }
    if (l < 16) {
#pragma unroll
        for (int n = 0; n < 2; ++n) {
            const int col = wn * 32 + n * 16 + l;
            atomicAdd(&stats[col], s1[n]);
            atomicAdd(&stats[N2DIM + col], s2[n]);
        }
    }
}

// ---------------------------------------------------------------------------
// K6: out = relu(bn1(y1)), BN1 finalize inlined per block.
// ---------------------------------------------------------------------------
__global__ __launch_bounds__(256) void bn_out_kernel(
    const float* __restrict__ Y1, const float* __restrict__ stats1,
    const float* __restrict__ g1, const float* __restrict__ beta1,
    float* __restrict__ out)
{
    __shared__ float sgm[N2DIM], sga[N2DIM];
    const int tid = threadIdx.x;
    if (tid < N2DIM) {
        const float inv = 1.0f / (float)M_TOT;
        float mean = stats1[tid] * inv;
        float var  = stats1[N2DIM + tid] * inv - mean * mean;
        float m = g1[tid] * rsqrtf(var + 1e-5f);
        sgm[tid] = m;
        sga[tid] = beta1[tid] - mean * m;
    }
    __syncthreads();

    const int total = M_TOT * N2DIM / 4;
    for (int i = blockIdx.x * 256 + tid; i < total; i += gridDim.x * 256) {
        float4 v = ((const float4*)Y1)[i];
        const int cg = (i & 31) * 4;
        float4 m = *(const float4*)(sgm + cg);
        float4 a = *(const float4*)(sga + cg);
        float4 o;
        o.x = fmaxf(fmaf(v.x, m.x, a.x), 0.f);
        o.y = fmaxf(fmaf(v.y, m.y, a.y), 0.f);
        o.z = fmaxf(fmaf(v.z, m.z, a.z), 0.f);
        o.w = fmaxf(fmaf(v.w, m.w, a.w), 0.f);
        ((float4*)out)[i] = o;
    }
}

// ---------------------------------------------------------------------------
// launch
// ---------------------------------------------------------------------------
extern "C" void kernel_launch(void* const* d_in, const int* in_sizes, int n_in,
                              void* d_out, int out_size, void* d_ws, size_t ws_size,
                              hipStream_t stream)
{
    const float* uxyz  = (const float*)d_in[0];
    const float* kxyz  = (const float*)d_in[1];
    const float* upts  = (const float*)d_in[2];
    const float* kpts  = (const float*)d_in[3];
    const float* W0    = (const float*)d_in[4];
    const float* g0    = (const float*)d_in[6];
    const float* beta0 = (const float*)d_in[7];
    const float* W1    = (const float*)d_in[8];
    const float* g1    = (const float*)d_in[10];
    const float* beta1 = (const float*)d_in[11];
    float* out = (float*)d_out;

    char* ws = (char*)d_ws;
    const size_t off_y1 = 0;                 // y1 f32 [M][128] = 33.5MB
    const size_t off_wx = 35651584;          // widx [M] uint4 = 1MB
    const size_t off_z  = 36700160;          // Z bf16 [16384][256] = 8.4MB
    const size_t off_y0 = 50331648;          // y0 bf16 [M][256]; cand+kpack alias
    const size_t off_wa = 83886080;          // Wa bf16 [256][128] = 64KB
    const size_t off_wb = 83951616;          // Wb bf16 [256][256] = 128KB
    const size_t off_w1 = 84082688;          // W1 bf16 = 64KB
    const size_t off_f  = 84148224;          // stats

    float*          y1   = (float*)(ws + off_y1);
    uint4*          widx = (uint4*)(ws + off_wx);
    unsigned short* Zb   = (unsigned short*)(ws + off_z);
    unsigned short* y0   = (unsigned short*)(ws + off_y0);
    unsigned int*   cand = (unsigned int*)(ws + off_y0);          // 6.3MB
    float4*         kpack = (float4*)(ws + off_y0 + 8388608);     // 256KB
    unsigned short* wa   = (unsigned short*)(ws + off_wa);
    unsigned short* wb   = (unsigned short*)(ws + off_wb);
    unsigned short* wb1  = (unsigned short*)(ws + off_w1);
    float* F = (float*)(ws + off_f);
    float* stats0 = F;           // [512]
    float* stats1 = F + 512;     // [256]

    hipMemsetAsync(stats0, 0, 768 * sizeof(float), stream);

    cvt_w_kernel<<<384, 256, 0, stream>>>(W0, W1, kxyz, wa, wb, wb1, kpack);
    nn_cand_kernel<<<2048, 256, 0, stream>>>(uxyz, kpack, cand);
    merge_w_kernel<<<256, 256, 0, stream>>>(cand, kpack, uxyz, widx);
    zgemm_kernel<<<256, 512, 0, stream>>>(kpts, wb, Zb);
    gemm1c_kernel<<<512, 512, 0, stream>>>(upts, wa, Zb, widx, y0, stats0);
    gemm2_kernel<<<512, 512, 0, stream>>>(y0, wb1, stats0, g0, beta0, y1, stats1);
    bn_out_kernel<<<2048, 256, 0, stream>>>(y1, stats1, g1, beta1, out);
}

// Round 5
// 159.123 us; speedup vs baseline: 1.3726x; 1.3726x over previous
//
#include <hip/hip_runtime.h>
#include <hip/hip_bf16.h>

// ---------------------------------------------------------------------------
// PointNet Feature Propagation, MI355X (gfx950)
//   Algebra: y0 = upts@W0a^T + sum_j w_j * Z[idx_j],  Z = kpts@W0b^T
//   (interp commutes with 1x1 conv; validated R4: passed, absmax 0.03125)
//   K1a: chunked 3-NN scan (dot-form + med3 packed keys)
//   KZ:  zgemm  Z = bf16(kpts) @ W0b^T   [16384][256] bf16
//   K1b: merge+rescue -> gather Z rows -> xz = interp(Z) bf16 (R3 structure)
//   K1c: gemm1z U@Wa^T (128x128 tile, K=128) + xz add + stats0
//   K4:  gemm2 (BN0 finalize inline, BN0+ReLU fused A) -> y1 bf16
//   K6:  bn_out (BN1 finalize inline) -> out f32
// ---------------------------------------------------------------------------

typedef __attribute__((ext_vector_type(8))) short short8;
typedef __attribute__((ext_vector_type(4))) float f32x4;

#define BB 8
#define NN 8192
#define SS 2048
#define M_TOT (BB * NN)      // 65536 points
#define N1DIM 256
#define K2DIM 256
#define N2DIM 128
#define NCH 8
#define CHS (SS / NCH)
#define BK 64

#define KEY_MASK 0xFFFFF800u
#define IDX_MASK 0x7FFu

__device__ __forceinline__ unsigned short f2bf(float f) {
    unsigned int x = __float_as_uint(f);
    unsigned int r = x + 0x7fffu + ((x >> 16) & 1u);  // RNE
    return (unsigned short)(r >> 16);
}
__device__ __forceinline__ float bf2f(unsigned short u) {
    return __uint_as_float(((unsigned int)u) << 16);
}
__device__ __forceinline__ unsigned int med3_u32(unsigned int a, unsigned int b,
                                                 unsigned int c) {
    unsigned int r;
    asm("v_med3_u32 %0, %1, %2, %3" : "=v"(r) : "v"(a), "v"(b), "v"(c));
    return r;
}

// async 16B global->LDS DMA. LDS dest must be wave-uniform base + lane*16;
// global src is per-lane (pre-swizzled-source pattern).
__device__ __forceinline__ void gload_lds16(const void* g, void* lds) {
    __builtin_amdgcn_global_load_lds(
        (const __attribute__((address_space(1))) unsigned int*)g,
        (__attribute__((address_space(3))) unsigned int*)lds, 16, 0, 0);
}

// ---------------------------------------------------------------------------
// K1a: chunked 3-NN scan. 10 VALU/candidate, SGPR k-data.
// ---------------------------------------------------------------------------
__global__ __launch_bounds__(256) void nn_cand_kernel(
    const float* __restrict__ uxyz,
    const float4* __restrict__ kpack,   // [B][S] (x,y,z,|k|^2)
    unsigned int* __restrict__ cand)    // [NCH][3][M_TOT]
{
    const int tid  = threadIdx.x;
    const int bid  = blockIdx.x;
    const int ch   = bid & 7;
    const int tile = (bid >> 3) & 31;
    const int b    = bid >> 8;

    const int n = tile * 256 + tid;
    const float* up = uxyz + ((size_t)b * NN + n) * 3;
    const float ux = up[0], uy = up[1], uz = up[2];
    const float uu  = fmaf(ux, ux, fmaf(uy, uy, uz * uz));
    const float m2x = -2.0f * ux, m2y = -2.0f * uy, m2z = -2.0f * uz;

    const float4* kb = kpack + (size_t)b * SS + ch * CHS;
    const int base = ch * CHS;

    unsigned int k0 = 0xFFFFFFFFu, k1 = 0xFFFFFFFFu, k2 = 0xFFFFFFFFu;
#pragma unroll 8
    for (int s = 0; s < CHS; ++s) {
        float4 kc = kb[s];
        float d = kc.w + uu;
        d = fmaf(m2z, kc.z, d);
        d = fmaf(m2y, kc.y, d);
        d = fmaf(m2x, kc.x, d);
        d = fmaxf(d, 0.0f);
        unsigned int key = (__float_as_uint(d) & KEY_MASK) | (unsigned int)(base + s);
        unsigned int nk1 = med3_u32(k0, k1, key);
        unsigned int nk2 = med3_u32(k1, k2, key);
        k0 = min(k0, key);
        k1 = nk1;
        k2 = nk2;
    }

    const size_t pt = (size_t)b * NN + n;
    cand[(size_t)(ch * 3 + 0) * M_TOT + pt] = k0;
    cand[(size_t)(ch * 3 + 1) * M_TOT + pt] = k1;
    cand[(size_t)(ch * 3 + 2) * M_TOT + pt] = k2;
}

// ---------------------------------------------------------------------------
// K0: split W0 -> Wa [256][128] / Wb [256][256] bf16; W1 bf16; kpack.
// ---------------------------------------------------------------------------
__global__ __launch_bounds__(256) void cvt_w_kernel(
    const float* __restrict__ W0, const float* __restrict__ W1,
    const float* __restrict__ kxyz,
    unsigned short* __restrict__ Wa, unsigned short* __restrict__ Wb,
    unsigned short* __restrict__ Wb1, float4* __restrict__ kpack)
{
    int i = blockIdx.x * 256 + threadIdx.x;
    if (i < 256 * 384) {
        int o = i / 384, c = i - o * 384;
        unsigned short v = f2bf(W0[i]);
        if (c < 128) Wa[o * 128 + c] = v;
        else         Wb[o * 256 + (c - 128)] = v;
    }
    if (i < N2DIM * K2DIM) Wb1[i] = f2bf(W1[i]);
    if (i < BB * SS) {
        const float* p = kxyz + (size_t)i * 3;
        float px = p[0], py = p[1], pz = p[2];
        kpack[i] = make_float4(px, py, pz, fmaf(px, px, fmaf(py, py, pz * pz)));
    }
}

// ---------------------------------------------------------------------------
// KZ: Z = bf16(kpts) @ Wb^T.  128x128 tiles (N-split 2), BK=64, dbuf,
// A reg-staged f32->bf16, B global_load_lds, XOR swizzle. (validated R4)
// ---------------------------------------------------------------------------
__global__ __launch_bounds__(512, 4) void zgemm_kernel(
    const float* __restrict__ kpts,        // [16384][256] f32
    const unsigned short* __restrict__ Wb, // [256][256] bf16
    unsigned short* __restrict__ Z)        // [16384][256] bf16
{
    __shared__ __align__(128) unsigned char smem[2 * 32768];

    const int tid = threadIdx.x;
    const int l = tid & 63, w = tid >> 6;
    const int wm = w >> 2, wn = w & 3;
    const int mt = blockIdx.x >> 1, nh = blockIdx.x & 1;
    const int row0 = mt * 128;
    const int srow = l >> 3, sbo = (l & 7) * 16;
    const int lr = tid >> 2, lcq = tid & 3;

    f32x4 acc[4][2];
#pragma unroll
    for (int m = 0; m < 4; ++m)
#pragma unroll
        for (int n = 0; n < 2; ++n) {
            f32x4 z = {0.f, 0.f, 0.f, 0.f};
            acc[m][n] = z;
        }

    const unsigned char* Bb = (const unsigned char*)Wb + (size_t)nh * 128 * 512;
    float4 af0, af1, af2, af3;

    auto issueA = [&](int t) {
        const float* src = kpts + (size_t)(row0 + lr) * 256 + t * 64 + lcq * 16;
        af0 = ((const float4*)src)[0];
        af1 = ((const float4*)src)[1];
        af2 = ((const float4*)src)[2];
        af3 = ((const float4*)src)[3];
    };
    auto stageB = [&](int buf, int t) {
        unsigned char* Bl = smem + buf * 32768 + 16384;
#pragma unroll
        for (int i = 0; i < 2; ++i) {
            const int r = w * 16 + i * 8 + srow;
            gload_lds16(Bb + (size_t)r * 512 + t * 128 + (sbo ^ ((r & 7) << 4)),
                        Bl + r * 128 + sbo);
        }
    };
    auto xformA = [&](int buf) {
        unsigned char* Al = smem + buf * 32768;
        short8 o0, o1;
        o0[0] = (short)f2bf(af0.x); o0[1] = (short)f2bf(af0.y);
        o0[2] = (short)f2bf(af0.z); o0[3] = (short)f2bf(af0.w);
        o0[4] = (short)f2bf(af1.x); o0[5] = (short)f2bf(af1.y);
        o0[6] = (short)f2bf(af1.z); o0[7] = (short)f2bf(af1.w);
        o1[0] = (short)f2bf(af2.x); o1[1] = (short)f2bf(af2.y);
        o1[2] = (short)f2bf(af2.z); o1[3] = (short)f2bf(af2.w);
        o1[4] = (short)f2bf(af3.x); o1[5] = (short)f2bf(af3.y);
        o1[6] = (short)f2bf(af3.z); o1[7] = (short)f2bf(af3.w);
        const int bo = lcq * 32;
        *(short8*)(Al + lr * 128 + ((bo) ^ ((lr & 7) << 4))) = o0;
        *(short8*)(Al + lr * 128 + ((bo + 16) ^ ((lr & 7) << 4))) = o1;
    };
    auto compute = [&](int buf) {
        const unsigned char* Al = smem + buf * 32768;
        const unsigned char* Bl = Al + 16384;
#pragma unroll
        for (int ks = 0; ks < 2; ++ks) {
            const int bo = ks * 64 + (l >> 4) * 16;
            short8 a[4], bq[2];
#pragma unroll
            for (int m = 0; m < 4; ++m) {
                const int r = wm * 64 + m * 16 + (l & 15);
                a[m] = *(const short8*)(Al + r * 128 + (bo ^ ((r & 7) << 4)));
            }
#pragma unroll
            for (int n = 0; n < 2; ++n) {
                const int r = wn * 32 + n * 16 + (l & 15);
                bq[n] = *(const short8*)(Bl + r * 128 + (bo ^ ((r & 7) << 4)));
            }
#pragma unroll
            for (int m = 0; m < 4; ++m)
#pragma unroll
                for (int n = 0; n < 2; ++n)
                    acc[m][n] = __builtin_amdgcn_mfma_f32_16x16x32_bf16(
                        a[m], bq[n], acc[m][n], 0, 0, 0);
        }
    };

    issueA(0);
    stageB(0, 0);
    xformA(0);
    __syncthreads();
#pragma unroll
    for (int t = 0; t < 4; ++t) {
        const int cur = t & 1;
        if (t + 1 < 4) { issueA(t + 1); stageB(cur ^ 1, t + 1); }
        compute(cur);
        if (t + 1 < 4) xformA(cur ^ 1);
        __syncthreads();
    }

#pragma unroll
    for (int m = 0; m < 4; ++m) {
        const int row = row0 + wm * 64 + m * 16 + (l >> 4) * 4;
#pragma unroll
        for (int n = 0; n < 2; ++n) {
            const int col = nh * 128 + wn * 32 + n * 16 + (l & 15);
            f32x4 v = acc[m][n];
#pragma unroll
            for (int r = 0; r < 4; ++r)
                Z[(size_t)(row + r) * 256 + col] = f2bf(v[r]);
        }
    }
}

// ---------------------------------------------------------------------------
// K1b: merge 24 keys -> quantized top-6 -> exact rescue top-3 -> gather Z
//      rows (512B bf16, L2-hot) -> xz = interp(Z) bf16.  (R3 structure)
// ---------------------------------------------------------------------------
__global__ __launch_bounds__(256) void merge_interp_z_kernel(
    const unsigned int* __restrict__ cand,   // [NCH][3][M_TOT]
    const float4* __restrict__ kpack,        // [B][S]
    const float* __restrict__ uxyz,
    const unsigned short* __restrict__ Z,    // [16384][256] bf16
    unsigned short* __restrict__ xz)         // [M][256] bf16
{
    __shared__ int   sidx[64][3];
    __shared__ float sw[64][3];

    const int tid = threadIdx.x;
    const int bid = blockIdx.x;
    const int b   = bid & 7;
    const int pn  = (bid >> 3) * 64;

    if (tid < 64) {
        const size_t pt = (size_t)b * NN + pn + tid;

        unsigned int k[6];
#pragma unroll
        for (int i = 0; i < 6; ++i) k[i] = 0xFFFFFFFFu;
#pragma unroll
        for (int ch = 0; ch < NCH; ++ch) {
#pragma unroll
            for (int j = 0; j < 3; ++j) {
                unsigned int t = cand[(size_t)(ch * 3 + j) * M_TOT + pt];
#pragma unroll
                for (int i = 0; i < 6; ++i) {
                    unsigned int a = min(k[i], t);
                    t = max(k[i], t);
                    k[i] = a;
                }
            }
        }

        const float* up = uxyz + pt * 3;
        const float ux = up[0], uy = up[1], uz = up[2];
        const float4* kpb4 = kpack + (size_t)b * SS;
        unsigned long long e[6];
#pragma unroll
        for (int i = 0; i < 6; ++i) {
            unsigned int idx = k[i] & IDX_MASK;
            float4 kc = kpb4[idx];
            float dx = kc.x - ux, dy = kc.y - uy, dz = kc.z - uz;
            float d = fmaf(dx, dx, fmaf(dy, dy, dz * dz));
            e[i] = ((unsigned long long)__float_as_uint(d) << 32) | idx;
        }
#pragma unroll
        for (int i = 0; i < 3; ++i)
#pragma unroll
            for (int j = i + 1; j < 6; ++j)
                if (e[j] < e[i]) { unsigned long long t = e[i]; e[i] = e[j]; e[j] = t; }

        float d0 = __uint_as_float((unsigned int)(e[0] >> 32));
        float d1 = __uint_as_float((unsigned int)(e[1] >> 32));
        float d2 = __uint_as_float((unsigned int)(e[2] >> 32));
        float r0 = 1.0f / (d0 + 1e-8f);
        float r1 = 1.0f / (d1 + 1e-8f);
        float r2 = 1.0f / (d2 + 1e-8f);
        float rs = 1.0f / (r0 + r1 + r2);
        sidx[tid][0] = (int)(e[0] & IDX_MASK);
        sidx[tid][1] = (int)(e[1] & IDX_MASK);
        sidx[tid][2] = (int)(e[2] & IDX_MASK);
        sw[tid][0] = r0 * rs; sw[tid][1] = r1 * rs; sw[tid][2] = r2 * rs;
    }
    __syncthreads();

    const int wv = tid >> 6, lane = tid & 63;
    const unsigned short* Zb = Z + (size_t)b * SS * 256;
    for (int p = wv; p < 64; p += 4) {
        const int j0 = sidx[p][0], j1 = sidx[p][1], j2 = sidx[p][2];
        const float w0 = sw[p][0], w1 = sw[p][1], w2 = sw[p][2];

        ushort4 z0 = *(const ushort4*)(Zb + (size_t)j0 * 256 + lane * 4);
        ushort4 z1 = *(const ushort4*)(Zb + (size_t)j1 * 256 + lane * 4);
        ushort4 z2 = *(const ushort4*)(Zb + (size_t)j2 * 256 + lane * 4);
        ushort4 o;
        o.x = f2bf(fmaf(w2, bf2f(z2.x), fmaf(w1, bf2f(z1.x), w0 * bf2f(z0.x))));
        o.y = f2bf(fmaf(w2, bf2f(z2.y), fmaf(w1, bf2f(z1.y), w0 * bf2f(z0.y))));
        o.z = f2bf(fmaf(w2, bf2f(z2.z), fmaf(w1, bf2f(z1.z), w0 * bf2f(z0.z))));
        o.w = f2bf(fmaf(w2, bf2f(z2.w), fmaf(w1, bf2f(z1.w), w0 * bf2f(z0.w))));
        *(ushort4*)(xz + ((size_t)b * NN + pn + p) * 256 + lane * 4) = o;
    }
}

// ---------------------------------------------------------------------------
// K1c: gemm1z  y0 = upts@Wa^T + xz; stats0.
// Tile 128x128 (nh split), K=128 single-stage: A reg-cvt 32KB + B gload 32KB
// = 64KB LDS -> 2 blocks/CU. Epilogue: streamed xz add, R3 store pattern.
// ---------------------------------------------------------------------------
__global__ __launch_bounds__(512, 4) void gemm1z_kernel(
    const float* __restrict__ upts,          // [M][128] f32
    const unsigned short* __restrict__ Wa,   // [256][128] bf16
    const unsigned short* __restrict__ xz,   // [M][256] bf16
    unsigned short* __restrict__ Y0,         // [M][256] bf16
    float* __restrict__ stats)               // [512]: sum|sumsq
{
    __shared__ __align__(128) unsigned char smem[65536];

    const int tid = threadIdx.x;
    const int l = tid & 63, w = tid >> 6;
    const int wm = w >> 2, wn = w & 3;
    const int mt = blockIdx.x >> 1, nh = blockIdx.x & 1;
    const int row0 = mt * 128;
    const int lr = tid >> 2, lcq = tid & 3;

    // ---- stage B: Wa[nh*128 + r] 128 rows x 256B (gload, pre-swz source) ----
    {
        const unsigned char* Bb = (const unsigned char*)Wa + (size_t)nh * 128 * 256;
#pragma unroll
        for (int i = 0; i < 4; ++i) {
            const int r = w * 16 + i * 4 + (l >> 4);
            gload_lds16(Bb + (size_t)r * 256 + (((l & 15) * 16) ^ ((r & 7) << 4)),
                        smem + 32768 + r * 256 + (l & 15) * 16);
        }
    }
    // ---- stage A: upts f32 -> bf16, swizzled ds_write (rows 256B) ----
    {
        const float* src = upts + (size_t)(row0 + lr) * 128 + lcq * 32;
        float4 f[8];
#pragma unroll
        for (int q = 0; q < 8; ++q) f[q] = ((const float4*)src)[q];
#pragma unroll
        for (int q = 0; q < 4; ++q) {
            float4 fa = f[q * 2], fb = f[q * 2 + 1];
            short8 o;
            o[0] = (short)f2bf(fa.x); o[1] = (short)f2bf(fa.y);
            o[2] = (short)f2bf(fa.z); o[3] = (short)f2bf(fa.w);
            o[4] = (short)f2bf(fb.x); o[5] = (short)f2bf(fb.y);
            o[6] = (short)f2bf(fb.z); o[7] = (short)f2bf(fb.w);
            *(short8*)(smem + lr * 256 +
                       ((lcq * 64 + q * 16) ^ ((lr & 7) << 4))) = o;
        }
    }
    __syncthreads();

    // ---- GEMM: K=128, 4 ks, 32 MFMA/wave ----
    f32x4 acc[4][2];
#pragma unroll
    for (int m = 0; m < 4; ++m)
#pragma unroll
        for (int n = 0; n < 2; ++n) {
            f32x4 z = {0.f, 0.f, 0.f, 0.f};
            acc[m][n] = z;
        }
#pragma unroll
    for (int ks = 0; ks < 4; ++ks) {
        const int bo = ks * 64 + (l >> 4) * 16;
        short8 a[4], bq[2];
#pragma unroll
        for (int m = 0; m < 4; ++m) {
            const int r = wm * 64 + m * 16 + (l & 15);
            a[m] = *(const short8*)(smem + r * 256 + (bo ^ ((r & 7) << 4)));
        }
#pragma unroll
        for (int n = 0; n < 2; ++n) {
            const int r = wn * 32 + n * 16 + (l & 15);
            bq[n] = *(const short8*)(smem + 32768 + r * 256 + (bo ^ ((r & 7) << 4)));
        }
#pragma unroll
        for (int m = 0; m < 4; ++m)
#pragma unroll
            for (int n = 0; n < 2; ++n)
                acc[m][n] = __builtin_amdgcn_mfma_f32_16x16x32_bf16(
                    a[m], bq[n], acc[m][n], 0, 0, 0);
    }

    // ---- epilogue: xz add (streamed, line-friendly), Y0 write, stats ----
    float s1[2] = {0.f, 0.f}, s2[2] = {0.f, 0.f};
#pragma unroll
    for (int m = 0; m < 4; ++m) {
#pragma unroll
        for (int r = 0; r < 4; ++r) {
            const int row = row0 + wm * 64 + m * 16 + (l >> 4) * 4 + r;
#pragma unroll
            for (int n = 0; n < 2; ++n) {
                const int col = nh * 128 + wn * 32 + n * 16 + (l & 15);
                float f = acc[m][n][r] + bf2f(xz[(size_t)row * 256 + col]);
                Y0[(size_t)row * 256 + col] = f2bf(f);
                s1[n] += f;
                s2[n] += f * f;
            }
        }
    }
#pragma unroll
    for (int n = 0; n < 2; ++n) {
        s1[n] += __shfl_xor(s1[n], 16, 64);
        s1[n] += __shfl_xor(s1[n], 32, 64);
        s2[n] += __shfl_xor(s2[n], 16, 64);
        s2[n] += __shfl_xor(s2[n], 32, 64);
    }
    if (l < 16) {
#pragma unroll
        for (int n = 0; n < 2; ++n) {
            const int col = nh * 128 + wn * 32 + n * 16 + l;
            atomicAdd(&stats[col], s1[n]);
            atomicAdd(&stats[N1DIM + col], s2[n]);
        }
    }
}

// ---------------------------------------------------------------------------
// K4: GEMM2  y1 = relu(bn0(y0)) @ W1^T  (R3-proven; Y1 now bf16)
// ---------------------------------------------------------------------------
#define G2_NT (K2DIM / BK)   // 4
__global__ __launch_bounds__(512, 4) void gemm2_kernel(
    const unsigned short* __restrict__ Y0,
    const unsigned short* __restrict__ Wb,
    const float* __restrict__ stats0,
    const float* __restrict__ g0,
    const float* __restrict__ beta0,
    unsigned short* __restrict__ Y1,         // [M][128] bf16
    float* __restrict__ stats)
{
    __shared__ __align__(128) unsigned char smem[2 * 32768];
    __shared__ float sgm[K2DIM], sga[K2DIM];

    const int tid = threadIdx.x;
    const int l = tid & 63, w = tid >> 6;
    const int wm = w >> 2, wn = w & 3;
    const int row0 = blockIdx.x * 128;
    const int srow = l >> 3;
    const int sbo  = (l & 7) * 16;
    const int lr  = tid >> 2;
    const int lcq = tid & 3;

    f32x4 acc[4][2];
#pragma unroll
    for (int m = 0; m < 4; ++m)
#pragma unroll
        for (int n = 0; n < 2; ++n) {
            f32x4 z = {0.f, 0.f, 0.f, 0.f};
            acc[m][n] = z;
        }

    const unsigned char* Bb = (const unsigned char*)Wb;
    short8 areg0, areg1;

    auto issueA = [&](int t) {
        const unsigned short* src = Y0 + (size_t)(row0 + lr) * K2DIM + t * BK + lcq * 16;
        areg0 = *(const short8*)src;
        areg1 = *(const short8*)(src + 8);
    };
    auto stageB = [&](int buf, int t) {
        unsigned char* Bl = smem + buf * 32768 + 16384;
        const int k0b = t * (BK * 2);
#pragma unroll
        for (int i = 0; i < 2; ++i) {
            const int r = w * 16 + i * 8 + srow;
            gload_lds16(Bb + (size_t)r * (K2DIM * 2) + k0b + (sbo ^ ((r & 7) << 4)),
                        Bl + r * 128 + sbo);
        }
    };
    auto xformA = [&](int buf, int t) {
        unsigned char* Al = smem + buf * 32768;
        const int kb = t * BK + lcq * 16;
        short8 o0, o1;
#pragma unroll
        for (int j = 0; j < 8; ++j) {
            float f = bf2f((unsigned short)areg0[j]);
            f = fmaxf(fmaf(f, sgm[kb + j], sga[kb + j]), 0.f);
            o0[j] = (short)f2bf(f);
            float g = bf2f((unsigned short)areg1[j]);
            g = fmaxf(fmaf(g, sgm[kb + 8 + j], sga[kb + 8 + j]), 0.f);
            o1[j] = (short)f2bf(g);
        }
        const int bo = lcq * 32;
        *(short8*)(Al + lr * 128 + ((bo) ^ ((lr & 7) << 4))) = o0;
        *(short8*)(Al + lr * 128 + ((bo + 16) ^ ((lr & 7) << 4))) = o1;
    };
    auto compute = [&](int buf) {
        const unsigned char* Al = smem + buf * 32768;
        const unsigned char* Bl = Al + 16384;
#pragma unroll
        for (int ks = 0; ks < 2; ++ks) {
            const int bo = ks * 64 + (l >> 4) * 16;
            short8 a[4], bq[2];
#pragma unroll
            for (int m = 0; m < 4; ++m) {
                const int r = wm * 64 + m * 16 + (l & 15);
                a[m] = *(const short8*)(Al + r * 128 + (bo ^ ((r & 7) << 4)));
            }
#pragma unroll
            for (int n = 0; n < 2; ++n) {
                const int r = wn * 32 + n * 16 + (l & 15);
                bq[n] = *(const short8*)(Bl + r * 128 + (bo ^ ((r & 7) << 4)));
            }
#pragma unroll
            for (int m = 0; m < 4; ++m)
#pragma unroll
                for (int n = 0; n < 2; ++n)
                    acc[m][n] = __builtin_amdgcn_mfma_f32_16x16x32_bf16(
                        a[m], bq[n], acc[m][n], 0, 0, 0);
        }
    };

    if (tid < K2DIM) {
        const float inv = 1.0f / (float)M_TOT;
        float mean = stats0[tid] * inv;
        float var  = stats0[N1DIM + tid] * inv - mean * mean;
        float m = g0[tid] * rsqrtf(var + 1e-5f);
        sgm[tid] = m;
        sga[tid] = beta0[tid] - mean * m;
    }
    issueA(0);
    stageB(0, 0);
    __syncthreads();
    xformA(0, 0);
    __syncthreads();

#pragma unroll
    for (int t = 0; t < G2_NT; ++t) {
        const int cur = t & 1;
        if (t + 1 < G2_NT) { issueA(t + 1); stageB(cur ^ 1, t + 1); }
        compute(cur);
        if (t + 1 < G2_NT) xformA(cur ^ 1, t + 1);
        __syncthreads();
    }

    float s1[2] = {0.f, 0.f}, s2[2] = {0.f, 0.f};
#pragma unroll
    for (int m = 0; m < 4; ++m) {
        const int row = row0 + wm * 64 + m * 16 + (l >> 4) * 4;
#pragma unroll
        for (int n = 0; n < 2; ++n) {
            const int col = wn * 32 + n * 16 + (l & 15);
            f32x4 v = acc[m][n];
#pragma unroll
            for (int r = 0; r < 4; ++r) {
                float f = v[r];
                Y1[(size_t)(row + r) * N2DIM + col] = f2bf(f);
                s1[n] += f;
                s2[n] += f * f;
            }
        }
    }
#pragma unroll
    for (int n = 0; n < 2; ++n) {
        s1[n] += __shfl_xor(s1[n], 16, 64);
        s1[n] += __shfl_xor(s1[n], 32, 64);
        s2[n] += __shfl_xor(s2[n], 16, 64);
        s2[n] += __shfl_xor(s2[n], 32, 64);
    }
    if (l < 16) {
#pragma unroll
        for (int n = 0; n < 2; ++n) {
            const int col = wn * 32 + n * 16 + l;
            atomicAdd(&stats[col], s1[n]);
            atomicAdd(&stats[N2DIM + col], s2[n]);
        }
    }
}

// ---------------------------------------------------------------------------
// K6: out = relu(bn1(y1)), BN1 finalize inlined; y1 bf16 in, out f32.
// ---------------------------------------------------------------------------
__global__ __launch_bounds__(256) void bn_out_kernel(
    const unsigned short* __restrict__ Y1, const float* __restrict__ stats1,
    const float* __restrict__ g1, const float* __restrict__ beta1,
    float* __restrict__ out)
{
    __shared__ float sgm[N2DIM], sga[N2DIM];
    const int tid = threadIdx.x;
    if (tid < N2DIM) {
        const float inv = 1.0f / (float)M_TOT;
        float mean = stats1[tid] * inv;
        float var  = stats1[N2DIM + tid] * inv - mean * mean;
        float m = g1[tid] * rsqrtf(var + 1e-5f);
        sgm[tid] = m;
        sga[tid] = beta1[tid] - mean * m;
    }
    __syncthreads();

    const int total = M_TOT * N2DIM / 8;
    for (int i = blockIdx.x * 256 + tid; i < total; i += gridDim.x * 256) {
        short8 v = ((const short8*)Y1)[i];
        const int cg = (i & 15) * 8;
        float4 o1, o2;
        o1.x = fmaxf(fmaf(bf2f((unsigned short)v[0]), sgm[cg + 0], sga[cg + 0]), 0.f);
        o1.y = fmaxf(fmaf(bf2f((unsigned short)v[1]), sgm[cg + 1], sga[cg + 1]), 0.f);
        o1.z = fmaxf(fmaf(bf2f((unsigned short)v[2]), sgm[cg + 2], sga[cg + 2]), 0.f);
        o1.w = fmaxf(fmaf(bf2f((unsigned short)v[3]), sgm[cg + 3], sga[cg + 3]), 0.f);
        o2.x = fmaxf(fmaf(bf2f((unsigned short)v[4]), sgm[cg + 4], sga[cg + 4]), 0.f);
        o2.y = fmaxf(fmaf(bf2f((unsigned short)v[5]), sgm[cg + 5], sga[cg + 5]), 0.f);
        o2.z = fmaxf(fmaf(bf2f((unsigned short)v[6]), sgm[cg + 6], sga[cg + 6]), 0.f);
        o2.w = fmaxf(fmaf(bf2f((unsigned short)v[7]), sgm[cg + 7], sga[cg + 7]), 0.f);
        ((float4*)out)[i * 2]     = o1;
        ((float4*)out)[i * 2 + 1] = o2;
    }
}

// ---------------------------------------------------------------------------
// launch
// ---------------------------------------------------------------------------
extern "C" void kernel_launch(void* const* d_in, const int* in_sizes, int n_in,
                              void* d_out, int out_size, void* d_ws, size_t ws_size,
                              hipStream_t stream)
{
    const float* uxyz  = (const float*)d_in[0];
    const float* kxyz  = (const float*)d_in[1];
    const float* upts  = (const float*)d_in[2];
    const float* kpts  = (const float*)d_in[3];
    const float* W0    = (const float*)d_in[4];
    const float* g0    = (const float*)d_in[6];
    const float* beta0 = (const float*)d_in[7];
    const float* W1    = (const float*)d_in[8];
    const float* g1    = (const float*)d_in[10];
    const float* beta1 = (const float*)d_in[11];
    float* out = (float*)d_out;

    char* ws = (char*)d_ws;
    const size_t off_xz = 0;                 // xz bf16 [M][256] 33.5MB; y1 bf16 aliases (16.7MB)
    const size_t off_y0 = 33554432;          // y0 bf16 [M][256]; cand(6.3MB)+kpack alias
    const size_t off_z  = 67108864;          // Z bf16 [16384][256] 8.4MB
    const size_t off_w  = 75497472;          // weights + stats

    unsigned short* xz   = (unsigned short*)(ws + off_xz);
    unsigned short* y1   = (unsigned short*)(ws + off_xz);        // aliases xz
    unsigned short* y0   = (unsigned short*)(ws + off_y0);
    unsigned int*   cand = (unsigned int*)(ws + off_y0);          // 6.3MB
    float4*         kpack = (float4*)(ws + off_y0 + 8388608);     // 256KB
    unsigned short* Zb   = (unsigned short*)(ws + off_z);
    unsigned short* wa   = (unsigned short*)(ws + off_w);
    unsigned short* wb   = (unsigned short*)(ws + off_w + 65536);
    unsigned short* wb1  = (unsigned short*)(ws + off_w + 196608);
    float* F = (float*)(ws + off_w + 262144);
    float* stats0 = F;           // [512]
    float* stats1 = F + 512;     // [256]

    hipMemsetAsync(stats0, 0, 768 * sizeof(float), stream);

    cvt_w_kernel<<<384, 256, 0, stream>>>(W0, W1, kxyz, wa, wb, wb1, kpack);
    nn_cand_kernel<<<2048, 256, 0, stream>>>(uxyz, kpack, cand);
    zgemm_kernel<<<256, 512, 0, stream>>>(kpts, wb, Zb);
    merge_interp_z_kernel<<<1024, 256, 0, stream>>>(cand, kpack, uxyz, Zb, xz);
    gemm1z_kernel<<<1024, 512, 0, stream>>>(upts, wa, xz, y0, stats0);
    gemm2_kernel<<<512, 512, 0, stream>>>(y0, wb1, stats0, g0, beta0, y1, stats1);
    bn_out_kernel<<<2048, 256, 0, stream>>>(y1, stats1, g1, beta1, out);
}

// Round 6
// 155.411 us; speedup vs baseline: 1.4054x; 1.0239x over previous
//
#include <hip/hip_runtime.h>
#include <hip/hip_bf16.h>

// ---------------------------------------------------------------------------
// PointNet Feature Propagation, MI355X (gfx950)
//   Algebra: y0 = upts@W0a^T + sum_j w_j * Z[idx_j],  Z = kpts@W0b^T
//   K1a: chunked 3-NN scan (dot-form + med3 packed keys)
//   KZ:  zgemm  Z = bf16(kpts) @ W0b^T   [16384][256] bf16
//   K1b: merge+rescue -> gather Z rows -> xz = interp(Z) bf16
//   K1c: gemm1z U@Wa^T (128x128 tile, K=128 as 2x64 halves, 128B LDS rows)
//        + xz add + stats0
//   K4:  gemm2 (BN0 finalize inline, BN0+ReLU fused A) -> y1 bf16
//   K6:  bn_out (BN1 finalize inline) -> out f32
//   stats zeroed inside cvt_w (no hipMemsetAsync -> kills 41us fill dispatch)
// ---------------------------------------------------------------------------

typedef __attribute__((ext_vector_type(8))) short short8;
typedef __attribute__((ext_vector_type(4))) float f32x4;

#define BB 8
#define NN 8192
#define SS 2048
#define M_TOT (BB * NN)      // 65536 points
#define N1DIM 256
#define K2DIM 256
#define N2DIM 128
#define NCH 8
#define CHS (SS / NCH)
#define BK 64

#define KEY_MASK 0xFFFFF800u
#define IDX_MASK 0x7FFu

__device__ __forceinline__ unsigned short f2bf(float f) {
    unsigned int x = __float_as_uint(f);
    unsigned int r = x + 0x7fffu + ((x >> 16) & 1u);  // RNE
    return (unsigned short)(r >> 16);
}
__device__ __forceinline__ float bf2f(unsigned short u) {
    return __uint_as_float(((unsigned int)u) << 16);
}
__device__ __forceinline__ unsigned int med3_u32(unsigned int a, unsigned int b,
                                                 unsigned int c) {
    unsigned int r;
    asm("v_med3_u32 %0, %1, %2, %3" : "=v"(r) : "v"(a), "v"(b), "v"(c));
    return r;
}

// async 16B global->LDS DMA. LDS dest must be wave-uniform base + lane*16;
// global src is per-lane (pre-swizzled-source pattern).
__device__ __forceinline__ void gload_lds16(const void* g, void* lds) {
    __builtin_amdgcn_global_load_lds(
        (const __attribute__((address_space(1))) unsigned int*)g,
        (__attribute__((address_space(3))) unsigned int*)lds, 16, 0, 0);
}

// ---------------------------------------------------------------------------
// K1a: chunked 3-NN scan. 10 VALU/candidate, SGPR k-data.
// ---------------------------------------------------------------------------
__global__ __launch_bounds__(256) void nn_cand_kernel(
    const float* __restrict__ uxyz,
    const float4* __restrict__ kpack,   // [B][S] (x,y,z,|k|^2)
    unsigned int* __restrict__ cand)    // [NCH][3][M_TOT]
{
    const int tid  = threadIdx.x;
    const int bid  = blockIdx.x;
    const int ch   = bid & 7;
    const int tile = (bid >> 3) & 31;
    const int b    = bid >> 8;

    const int n = tile * 256 + tid;
    const float* up = uxyz + ((size_t)b * NN + n) * 3;
    const float ux = up[0], uy = up[1], uz = up[2];
    const float uu  = fmaf(ux, ux, fmaf(uy, uy, uz * uz));
    const float m2x = -2.0f * ux, m2y = -2.0f * uy, m2z = -2.0f * uz;

    const float4* kb = kpack + (size_t)b * SS + ch * CHS;
    const int base = ch * CHS;

    unsigned int k0 = 0xFFFFFFFFu, k1 = 0xFFFFFFFFu, k2 = 0xFFFFFFFFu;
#pragma unroll 8
    for (int s = 0; s < CHS; ++s) {
        float4 kc = kb[s];
        float d = kc.w + uu;
        d = fmaf(m2z, kc.z, d);
        d = fmaf(m2y, kc.y, d);
        d = fmaf(m2x, kc.x, d);
        d = fmaxf(d, 0.0f);
        unsigned int key = (__float_as_uint(d) & KEY_MASK) | (unsigned int)(base + s);
        unsigned int nk1 = med3_u32(k0, k1, key);
        unsigned int nk2 = med3_u32(k1, k2, key);
        k0 = min(k0, key);
        k1 = nk1;
        k2 = nk2;
    }

    const size_t pt = (size_t)b * NN + n;
    cand[(size_t)(ch * 3 + 0) * M_TOT + pt] = k0;
    cand[(size_t)(ch * 3 + 1) * M_TOT + pt] = k1;
    cand[(size_t)(ch * 3 + 2) * M_TOT + pt] = k2;
}

// ---------------------------------------------------------------------------
// K0: split W0 -> Wa [256][128] / Wb [256][256] bf16; W1 bf16; kpack;
//     zero stats (replaces hipMemsetAsync's 41us fill dispatch).
// ---------------------------------------------------------------------------
__global__ __launch_bounds__(256) void cvt_w_kernel(
    const float* __restrict__ W0, const float* __restrict__ W1,
    const float* __restrict__ kxyz,
    unsigned short* __restrict__ Wa, unsigned short* __restrict__ Wb,
    unsigned short* __restrict__ Wb1, float4* __restrict__ kpack,
    float* __restrict__ statsF)
{
    int i = blockIdx.x * 256 + threadIdx.x;
    if (blockIdx.x == 0) {
        for (int j = threadIdx.x; j < 768; j += 256) statsF[j] = 0.0f;
    }
    if (i < 256 * 384) {
        int o = i / 384, c = i - o * 384;
        unsigned short v = f2bf(W0[i]);
        if (c < 128) Wa[o * 128 + c] = v;
        else         Wb[o * 256 + (c - 128)] = v;
    }
    if (i < N2DIM * K2DIM) Wb1[i] = f2bf(W1[i]);
    if (i < BB * SS) {
        const float* p = kxyz + (size_t)i * 3;
        float px = p[0], py = p[1], pz = p[2];
        kpack[i] = make_float4(px, py, pz, fmaf(px, px, fmaf(py, py, pz * pz)));
    }
}

// ---------------------------------------------------------------------------
// KZ: Z = bf16(kpts) @ Wb^T.  128x128 tiles (N-split 2), BK=64, dbuf,
// A reg-staged f32->bf16, B global_load_lds, XOR swizzle. (validated R4/R5)
// ---------------------------------------------------------------------------
__global__ __launch_bounds__(512, 4) void zgemm_kernel(
    const float* __restrict__ kpts,        // [16384][256] f32
    const unsigned short* __restrict__ Wb, // [256][256] bf16
    unsigned short* __restrict__ Z)        // [16384][256] bf16
{
    __shared__ __align__(128) unsigned char smem[2 * 32768];

    const int tid = threadIdx.x;
    const int l = tid & 63, w = tid >> 6;
    const int wm = w >> 2, wn = w & 3;
    const int mt = blockIdx.x >> 1, nh = blockIdx.x & 1;
    const int row0 = mt * 128;
    const int srow = l >> 3, sbo = (l & 7) * 16;
    const int lr = tid >> 2, lcq = tid & 3;

    f32x4 acc[4][2];
#pragma unroll
    for (int m = 0; m < 4; ++m)
#pragma unroll
        for (int n = 0; n < 2; ++n) {
            f32x4 z = {0.f, 0.f, 0.f, 0.f};
            acc[m][n] = z;
        }

    const unsigned char* Bb = (const unsigned char*)Wb + (size_t)nh * 128 * 512;
    float4 af0, af1, af2, af3;

    auto issueA = [&](int t) {
        const float* src = kpts + (size_t)(row0 + lr) * 256 + t * 64 + lcq * 16;
        af0 = ((const float4*)src)[0];
        af1 = ((const float4*)src)[1];
        af2 = ((const float4*)src)[2];
        af3 = ((const float4*)src)[3];
    };
    auto stageB = [&](int buf, int t) {
        unsigned char* Bl = smem + buf * 32768 + 16384;
#pragma unroll
        for (int i = 0; i < 2; ++i) {
            const int r = w * 16 + i * 8 + srow;
            gload_lds16(Bb + (size_t)r * 512 + t * 128 + (sbo ^ ((r & 7) << 4)),
                        Bl + r * 128 + sbo);
        }
    };
    auto xformA = [&](int buf) {
        unsigned char* Al = smem + buf * 32768;
        short8 o0, o1;
        o0[0] = (short)f2bf(af0.x); o0[1] = (short)f2bf(af0.y);
        o0[2] = (short)f2bf(af0.z); o0[3] = (short)f2bf(af0.w);
        o0[4] = (short)f2bf(af1.x); o0[5] = (short)f2bf(af1.y);
        o0[6] = (short)f2bf(af1.z); o0[7] = (short)f2bf(af1.w);
        o1[0] = (short)f2bf(af2.x); o1[1] = (short)f2bf(af2.y);
        o1[2] = (short)f2bf(af2.z); o1[3] = (short)f2bf(af2.w);
        o1[4] = (short)f2bf(af3.x); o1[5] = (short)f2bf(af3.y);
        o1[6] = (short)f2bf(af3.z); o1[7] = (short)f2bf(af3.w);
        const int bo = lcq * 32;
        *(short8*)(Al + lr * 128 + ((bo) ^ ((lr & 7) << 4))) = o0;
        *(short8*)(Al + lr * 128 + ((bo + 16) ^ ((lr & 7) << 4))) = o1;
    };
    auto compute = [&](int buf) {
        const unsigned char* Al = smem + buf * 32768;
        const unsigned char* Bl = Al + 16384;
#pragma unroll
        for (int ks = 0; ks < 2; ++ks) {
            const int bo = ks * 64 + (l >> 4) * 16;
            short8 a[4], bq[2];
#pragma unroll
            for (int m = 0; m < 4; ++m) {
                const int r = wm * 64 + m * 16 + (l & 15);
                a[m] = *(const short8*)(Al + r * 128 + (bo ^ ((r & 7) << 4)));
            }
#pragma unroll
            for (int n = 0; n < 2; ++n) {
                const int r = wn * 32 + n * 16 + (l & 15);
                bq[n] = *(const short8*)(Bl + r * 128 + (bo ^ ((r & 7) << 4)));
            }
#pragma unroll
            for (int m = 0; m < 4; ++m)
#pragma unroll
                for (int n = 0; n < 2; ++n)
                    acc[m][n] = __builtin_amdgcn_mfma_f32_16x16x32_bf16(
                        a[m], bq[n], acc[m][n], 0, 0, 0);
        }
    };

    issueA(0);
    stageB(0, 0);
    xformA(0);
    __syncthreads();
#pragma unroll
    for (int t = 0; t < 4; ++t) {
        const int cur = t & 1;
        if (t + 1 < 4) { issueA(t + 1); stageB(cur ^ 1, t + 1); }
        compute(cur);
        if (t + 1 < 4) xformA(cur ^ 1);
        __syncthreads();
    }

#pragma unroll
    for (int m = 0; m < 4; ++m) {
        const int row = row0 + wm * 64 + m * 16 + (l >> 4) * 4;
#pragma unroll
        for (int n = 0; n < 2; ++n) {
            const int col = nh * 128 + wn * 32 + n * 16 + (l & 15);
            f32x4 v = acc[m][n];
#pragma unroll
            for (int r = 0; r < 4; ++r)
                Z[(size_t)(row + r) * 256 + col] = f2bf(v[r]);
        }
    }
}

// ---------------------------------------------------------------------------
// K1b: merge 24 keys -> quantized top-6 -> exact rescue top-3 -> gather Z
//      rows (512B bf16, L2-hot) -> xz = interp(Z) bf16.
// ---------------------------------------------------------------------------
__global__ __launch_bounds__(256) void merge_interp_z_kernel(
    const unsigned int* __restrict__ cand,   // [NCH][3][M_TOT]
    const float4* __restrict__ kpack,        // [B][S]
    const float* __restrict__ uxyz,
    const unsigned short* __restrict__ Z,    // [16384][256] bf16
    unsigned short* __restrict__ xz)         // [M][256] bf16
{
    __shared__ int   sidx[64][3];
    __shared__ float sw[64][3];

    const int tid = threadIdx.x;
    const int bid = blockIdx.x;
    const int b   = bid & 7;
    const int pn  = (bid >> 3) * 64;

    if (tid < 64) {
        const size_t pt = (size_t)b * NN + pn + tid;

        unsigned int k[6];
#pragma unroll
        for (int i = 0; i < 6; ++i) k[i] = 0xFFFFFFFFu;
#pragma unroll
        for (int ch = 0; ch < NCH; ++ch) {
#pragma unroll
            for (int j = 0; j < 3; ++j) {
                unsigned int t = cand[(size_t)(ch * 3 + j) * M_TOT + pt];
#pragma unroll
                for (int i = 0; i < 6; ++i) {
                    unsigned int a = min(k[i], t);
                    t = max(k[i], t);
                    k[i] = a;
                }
            }
        }

        const float* up = uxyz + pt * 3;
        const float ux = up[0], uy = up[1], uz = up[2];
        const float4* kpb4 = kpack + (size_t)b * SS;
        unsigned long long e[6];
#pragma unroll
        for (int i = 0; i < 6; ++i) {
            unsigned int idx = k[i] & IDX_MASK;
            float4 kc = kpb4[idx];
            float dx = kc.x - ux, dy = kc.y - uy, dz = kc.z - uz;
            float d = fmaf(dx, dx, fmaf(dy, dy, dz * dz));
            e[i] = ((unsigned long long)__float_as_uint(d) << 32) | idx;
        }
#pragma unroll
        for (int i = 0; i < 3; ++i)
#pragma unroll
            for (int j = i + 1; j < 6; ++j)
                if (e[j] < e[i]) { unsigned long long t = e[i]; e[i] = e[j]; e[j] = t; }

        float d0 = __uint_as_float((unsigned int)(e[0] >> 32));
        float d1 = __uint_as_float((unsigned int)(e[1] >> 32));
        float d2 = __uint_as_float((unsigned int)(e[2] >> 32));
        float r0 = 1.0f / (d0 + 1e-8f);
        float r1 = 1.0f / (d1 + 1e-8f);
        float r2 = 1.0f / (d2 + 1e-8f);
        float rs = 1.0f / (r0 + r1 + r2);
        sidx[tid][0] = (int)(e[0] & IDX_MASK);
        sidx[tid][1] = (int)(e[1] & IDX_MASK);
        sidx[tid][2] = (int)(e[2] & IDX_MASK);
        sw[tid][0] = r0 * rs; sw[tid][1] = r1 * rs; sw[tid][2] = r2 * rs;
    }
    __syncthreads();

    const int wv = tid >> 6, lane = tid & 63;
    const unsigned short* Zb = Z + (size_t)b * SS * 256;
    for (int p = wv; p < 64; p += 4) {
        const int j0 = sidx[p][0], j1 = sidx[p][1], j2 = sidx[p][2];
        const float w0 = sw[p][0], w1 = sw[p][1], w2 = sw[p][2];

        ushort4 z0 = *(const ushort4*)(Zb + (size_t)j0 * 256 + lane * 4);
        ushort4 z1 = *(const ushort4*)(Zb + (size_t)j1 * 256 + lane * 4);
        ushort4 z2 = *(const ushort4*)(Zb + (size_t)j2 * 256 + lane * 4);
        ushort4 o;
        o.x = f2bf(fmaf(w2, bf2f(z2.x), fmaf(w1, bf2f(z1.x), w0 * bf2f(z0.x))));
        o.y = f2bf(fmaf(w2, bf2f(z2.y), fmaf(w1, bf2f(z1.y), w0 * bf2f(z0.y))));
        o.z = f2bf(fmaf(w2, bf2f(z2.z), fmaf(w1, bf2f(z1.z), w0 * bf2f(z0.z))));
        o.w = f2bf(fmaf(w2, bf2f(z2.w), fmaf(w1, bf2f(z1.w), w0 * bf2f(z0.w))));
        *(ushort4*)(xz + ((size_t)b * NN + pn + p) * 256 + lane * 4) = o;
    }
}

// ---------------------------------------------------------------------------
// K1c: gemm1z  y0 = upts@Wa^T + xz; stats0.
// Tile 128x128 (nh split), K=128 as TWO 64-col halves, each a [128][128B]
// LDS tile (the proven conflict-free layout; 256B rows measured 1M conflicts
// in R5). A reg-cvt (2x16KB), B gload (2x16KB) = 64KB LDS, single-stage.
// ---------------------------------------------------------------------------
__global__ __launch_bounds__(512, 4) void gemm1z_kernel(
    const float* __restrict__ upts,          // [M][128] f32
    const unsigned short* __restrict__ Wa,   // [256][128] bf16
    const unsigned short* __restrict__ xz,   // [M][256] bf16
    unsigned short* __restrict__ Y0,         // [M][256] bf16
    float* __restrict__ stats)               // [512]: sum|sumsq
{
    // layout: A0 [0,16K) A1 [16K,32K) B0 [32K,48K) B1 [48K,64K)
    __shared__ __align__(128) unsigned char smem[65536];

    const int tid = threadIdx.x;
    const int l = tid & 63, w = tid >> 6;
    const int wm = w >> 2, wn = w & 3;
    const int mt = blockIdx.x >> 1, nh = blockIdx.x & 1;
    const int row0 = mt * 128;
    const int srow = l >> 3, sbo = (l & 7) * 16;
    const int lr = tid >> 2, lcq = tid & 3;

    // ---- stage B: Wa[nh*128 + r], rows 256B split into 2x128B halves ----
    {
        const unsigned char* Bb = (const unsigned char*)Wa + (size_t)nh * 128 * 256;
#pragma unroll
        for (int h = 0; h < 2; ++h)
#pragma unroll
            for (int i = 0; i < 2; ++i) {
                const int r = w * 16 + i * 8 + srow;
                gload_lds16(Bb + (size_t)r * 256 + h * 128 + (sbo ^ ((r & 7) << 4)),
                            smem + 32768 + h * 16384 + r * 128 + sbo);
            }
    }
    // ---- stage A: upts f32 -> bf16, swizzled ds_write into 128B-row halves ----
    {
        const float* src = upts + (size_t)(row0 + lr) * 128 + lcq * 32;
        float4 f[8];
#pragma unroll
        for (int q = 0; q < 8; ++q) f[q] = ((const float4*)src)[q];
        unsigned char* Ah = smem + (lcq >> 1) * 16384;
        const int cb = (lcq & 1) * 64;
#pragma unroll
        for (int q = 0; q < 4; ++q) {
            float4 fa = f[q * 2], fb = f[q * 2 + 1];
            short8 o;
            o[0] = (short)f2bf(fa.x); o[1] = (short)f2bf(fa.y);
            o[2] = (short)f2bf(fa.z); o[3] = (short)f2bf(fa.w);
            o[4] = (short)f2bf(fb.x); o[5] = (short)f2bf(fb.y);
            o[6] = (short)f2bf(fb.z); o[7] = (short)f2bf(fb.w);
            *(short8*)(Ah + lr * 128 + ((cb + q * 16) ^ ((lr & 7) << 4))) = o;
        }
    }
    __syncthreads();

    // ---- GEMM: K=128, 4 ks (half h = ks>>1), 32 MFMA/wave ----
    f32x4 acc[4][2];
#pragma unroll
    for (int m = 0; m < 4; ++m)
#pragma unroll
        for (int n = 0; n < 2; ++n) {
            f32x4 z = {0.f, 0.f, 0.f, 0.f};
            acc[m][n] = z;
        }
#pragma unroll
    for (int ks = 0; ks < 4; ++ks) {
        const unsigned char* Al = smem + (ks >> 1) * 16384;
        const unsigned char* Bl = smem + 32768 + (ks >> 1) * 16384;
        const int bo = (ks & 1) * 64 + (l >> 4) * 16;
        short8 a[4], bq[2];
#pragma unroll
        for (int m = 0; m < 4; ++m) {
            const int r = wm * 64 + m * 16 + (l & 15);
            a[m] = *(const short8*)(Al + r * 128 + (bo ^ ((r & 7) << 4)));
        }
#pragma unroll
        for (int n = 0; n < 2; ++n) {
            const int r = wn * 32 + n * 16 + (l & 15);
            bq[n] = *(const short8*)(Bl + r * 128 + (bo ^ ((r & 7) << 4)));
        }
#pragma unroll
        for (int m = 0; m < 4; ++m)
#pragma unroll
            for (int n = 0; n < 2; ++n)
                acc[m][n] = __builtin_amdgcn_mfma_f32_16x16x32_bf16(
                    a[m], bq[n], acc[m][n], 0, 0, 0);
    }

    // ---- epilogue: xz add, Y0 write, stats ----
    float s1[2] = {0.f, 0.f}, s2[2] = {0.f, 0.f};
#pragma unroll
    for (int m = 0; m < 4; ++m) {
#pragma unroll
        for (int r = 0; r < 4; ++r) {
            const int row = row0 + wm * 64 + m * 16 + (l >> 4) * 4 + r;
#pragma unroll
            for (int n = 0; n < 2; ++n) {
                const int col = nh * 128 + wn * 32 + n * 16 + (l & 15);
                float f = acc[m][n][r] + bf2f(xz[(size_t)row * 256 + col]);
                Y0[(size_t)row * 256 + col] = f2bf(f);
                s1[n] += f;
                s2[n] += f * f;
            }
        }
    }
#pragma unroll
    for (int n = 0; n < 2; ++n) {
        s1[n] += __shfl_xor(s1[n], 16, 64);
        s1[n] += __shfl_xor(s1[n], 32, 64);
        s2[n] += __shfl_xor(s2[n], 16, 64);
        s2[n] += __shfl_xor(s2[n], 32, 64);
    }
    if (l < 16) {
#pragma unroll
        for (int n = 0; n < 2; ++n) {
            const int col = nh * 128 + wn * 32 + n * 16 + l;
            atomicAdd(&stats[col], s1[n]);
            atomicAdd(&stats[N1DIM + col], s2[n]);
        }
    }
}

// ---------------------------------------------------------------------------
// K4: GEMM2  y1 = relu(bn0(y0)) @ W1^T  (R3-proven; Y1 bf16)
// ---------------------------------------------------------------------------
#define G2_NT (K2DIM / BK)   // 4
__global__ __launch_bounds__(512, 4) void gemm2_kernel(
    const unsigned short* __restrict__ Y0,
    const unsigned short* __restrict__ Wb,
    const float* __restrict__ stats0,
    const float* __restrict__ g0,
    const float* __restrict__ beta0,
    unsigned short* __restrict__ Y1,         // [M][128] bf16
    float* __restrict__ stats)
{
    __shared__ __align__(128) unsigned char smem[2 * 32768];
    __shared__ float sgm[K2DIM], sga[K2DIM];

    const int tid = threadIdx.x;
    const int l = tid & 63, w = tid >> 6;
    const int wm = w >> 2, wn = w & 3;
    const int row0 = blockIdx.x * 128;
    const int srow = l >> 3;
    const int sbo  = (l & 7) * 16;
    const int lr  = tid >> 2;
    const int lcq = tid & 3;

    f32x4 acc[4][2];
#pragma unroll
    for (int m = 0; m < 4; ++m)
#pragma unroll
        for (int n = 0; n < 2; ++n) {
            f32x4 z = {0.f, 0.f, 0.f, 0.f};
            acc[m][n] = z;
        }

    const unsigned char* Bb = (const unsigned char*)Wb;
    short8 areg0, areg1;

    auto issueA = [&](int t) {
        const unsigned short* src = Y0 + (size_t)(row0 + lr) * K2DIM + t * BK + lcq * 16;
        areg0 = *(const short8*)src;
        areg1 = *(const short8*)(src + 8);
    };
    auto stageB = [&](int buf, int t) {
        unsigned char* Bl = smem + buf * 32768 + 16384;
        const int k0b = t * (BK * 2);
#pragma unroll
        for (int i = 0; i < 2; ++i) {
            const int r = w * 16 + i * 8 + srow;
            gload_lds16(Bb + (size_t)r * (K2DIM * 2) + k0b + (sbo ^ ((r & 7) << 4)),
                        Bl + r * 128 + sbo);
        }
    };
    auto xformA = [&](int buf, int t) {
        unsigned char* Al = smem + buf * 32768;
        const int kb = t * BK + lcq * 16;
        short8 o0, o1;
#pragma unroll
        for (int j = 0; j < 8; ++j) {
            float f = bf2f((unsigned short)areg0[j]);
            f = fmaxf(fmaf(f, sgm[kb + j], sga[kb + j]), 0.f);
            o0[j] = (short)f2bf(f);
            float g = bf2f((unsigned short)areg1[j]);
            g = fmaxf(fmaf(g, sgm[kb + 8 + j], sga[kb + 8 + j]), 0.f);
            o1[j] = (short)f2bf(g);
        }
        const int bo = lcq * 32;
        *(short8*)(Al + lr * 128 + ((bo) ^ ((lr & 7) << 4))) = o0;
        *(short8*)(Al + lr * 128 + ((bo + 16) ^ ((lr & 7) << 4))) = o1;
    };
    auto compute = [&](int buf) {
        const unsigned char* Al = smem + buf * 32768;
        const unsigned char* Bl = Al + 16384;
#pragma unroll
        for (int ks = 0; ks < 2; ++ks) {
            const int bo = ks * 64 + (l >> 4) * 16;
            short8 a[4], bq[2];
#pragma unroll
            for (int m = 0; m < 4; ++m) {
                const int r = wm * 64 + m * 16 + (l & 15);
                a[m] = *(const short8*)(Al + r * 128 + (bo ^ ((r & 7) << 4)));
            }
#pragma unroll
            for (int n = 0; n < 2; ++n) {
                const int r = wn * 32 + n * 16 + (l & 15);
                bq[n] = *(const short8*)(Bl + r * 128 + (bo ^ ((r & 7) << 4)));
            }
#pragma unroll
            for (int m = 0; m < 4; ++m)
#pragma unroll
                for (int n = 0; n < 2; ++n)
                    acc[m][n] = __builtin_amdgcn_mfma_f32_16x16x32_bf16(
                        a[m], bq[n], acc[m][n], 0, 0, 0);
        }
    };

    if (tid < K2DIM) {
        const float inv = 1.0f / (float)M_TOT;
        float mean = stats0[tid] * inv;
        float var  = stats0[N1DIM + tid] * inv - mean * mean;
        float m = g0[tid] * rsqrtf(var + 1e-5f);
        sgm[tid] = m;
        sga[tid] = beta0[tid] - mean * m;
    }
    issueA(0);
    stageB(0, 0);
    __syncthreads();
    xformA(0, 0);
    __syncthreads();

#pragma unroll
    for (int t = 0; t < G2_NT; ++t) {
        const int cur = t & 1;
        if (t + 1 < G2_NT) { issueA(t + 1); stageB(cur ^ 1, t + 1); }
        compute(cur);
        if (t + 1 < G2_NT) xformA(cur ^ 1, t + 1);
        __syncthreads();
    }

    float s1[2] = {0.f, 0.f}, s2[2] = {0.f, 0.f};
#pragma unroll
    for (int m = 0; m < 4; ++m) {
        const int row = row0 + wm * 64 + m * 16 + (l >> 4) * 4;
#pragma unroll
        for (int n = 0; n < 2; ++n) {
            const int col = wn * 32 + n * 16 + (l & 15);
            f32x4 v = acc[m][n];
#pragma unroll
            for (int r = 0; r < 4; ++r) {
                float f = v[r];
                Y1[(size_t)(row + r) * N2DIM + col] = f2bf(f);
                s1[n] += f;
                s2[n] += f * f;
            }
        }
    }
#pragma unroll
    for (int n = 0; n < 2; ++n) {
        s1[n] += __shfl_xor(s1[n], 16, 64);
        s1[n] += __shfl_xor(s1[n], 32, 64);
        s2[n] += __shfl_xor(s2[n], 16, 64);
        s2[n] += __shfl_xor(s2[n], 32, 64);
    }
    if (l < 16) {
#pragma unroll
        for (int n = 0; n < 2; ++n) {
            const int col = wn * 32 + n * 16 + l;
            atomicAdd(&stats[col], s1[n]);
            atomicAdd(&stats[N2DIM + col], s2[n]);
        }
    }
}

// ---------------------------------------------------------------------------
// K6: out = relu(bn1(y1)), BN1 finalize inlined; y1 bf16 in, out f32.
// ---------------------------------------------------------------------------
__global__ __launch_bounds__(256) void bn_out_kernel(
    const unsigned short* __restrict__ Y1, const float* __restrict__ stats1,
    const float* __restrict__ g1, const float* __restrict__ beta1,
    float* __restrict__ out)
{
    __shared__ float sgm[N2DIM], sga[N2DIM];
    const int tid = threadIdx.x;
    if (tid < N2DIM) {
        const float inv = 1.0f / (float)M_TOT;
        float mean = stats1[tid] * inv;
        float var  = stats1[N2DIM + tid] * inv - mean * mean;
        float m = g1[tid] * rsqrtf(var + 1e-5f);
        sgm[tid] = m;
        sga[tid] = beta1[tid] - mean * m;
    }
    __syncthreads();

    const int total = M_TOT * N2DIM / 8;
    for (int i = blockIdx.x * 256 + tid; i < total; i += gridDim.x * 256) {
        short8 v = ((const short8*)Y1)[i];
        const int cg = (i & 15) * 8;
        float4 o1, o2;
        o1.x = fmaxf(fmaf(bf2f((unsigned short)v[0]), sgm[cg + 0], sga[cg + 0]), 0.f);
        o1.y = fmaxf(fmaf(bf2f((unsigned short)v[1]), sgm[cg + 1], sga[cg + 1]), 0.f);
        o1.z = fmaxf(fmaf(bf2f((unsigned short)v[2]), sgm[cg + 2], sga[cg + 2]), 0.f);
        o1.w = fmaxf(fmaf(bf2f((unsigned short)v[3]), sgm[cg + 3], sga[cg + 3]), 0.f);
        o2.x = fmaxf(fmaf(bf2f((unsigned short)v[4]), sgm[cg + 4], sga[cg + 4]), 0.f);
        o2.y = fmaxf(fmaf(bf2f((unsigned short)v[5]), sgm[cg + 5], sga[cg + 5]), 0.f);
        o2.z = fmaxf(fmaf(bf2f((unsigned short)v[6]), sgm[cg + 6], sga[cg + 6]), 0.f);
        o2.w = fmaxf(fmaf(bf2f((unsigned short)v[7]), sgm[cg + 7], sga[cg + 7]), 0.f);
        ((float4*)out)[i * 2]     = o1;
        ((float4*)out)[i * 2 + 1] = o2;
    }
}

// ---------------------------------------------------------------------------
// launch
// ---------------------------------------------------------------------------
extern "C" void kernel_launch(void* const* d_in, const int* in_sizes, int n_in,
                              void* d_out, int out_size, void* d_ws, size_t ws_size,
                              hipStream_t stream)
{
    const float* uxyz  = (const float*)d_in[0];
    const float* kxyz  = (const float*)d_in[1];
    const float* upts  = (const float*)d_in[2];
    const float* kpts  = (const float*)d_in[3];
    const float* W0    = (const float*)d_in[4];
    const float* g0    = (const float*)d_in[6];
    const float* beta0 = (const float*)d_in[7];
    const float* W1    = (const float*)d_in[8];
    const float* g1    = (const float*)d_in[10];
    const float* beta1 = (const float*)d_in[11];
    float* out = (float*)d_out;

    char* ws = (char*)d_ws;
    const size_t off_xz = 0;                 // xz bf16 [M][256] 33.5MB; y1 bf16 aliases (16.7MB)
    const size_t off_y0 = 33554432;          // y0 bf16 [M][256]; cand(6.3MB)+kpack alias
    const size_t off_z  = 67108864;          // Z bf16 [16384][256] 8.4MB
    const size_t off_w  = 75497472;          // weights + stats

    unsigned short* xz   = (unsigned short*)(ws + off_xz);
    unsigned short* y1   = (unsigned short*)(ws + off_xz);        // aliases xz
    unsigned short* y0   = (unsigned short*)(ws + off_y0);
    unsigned int*   cand = (unsigned int*)(ws + off_y0);          // 6.3MB
    float4*         kpack = (float4*)(ws + off_y0 + 8388608);     // 256KB
    unsigned short* Zb   = (unsigned short*)(ws + off_z);
    unsigned short* wa   = (unsigned short*)(ws + off_w);
    unsigned short* wb   = (unsigned short*)(ws + off_w + 65536);
    unsigned short* wb1  = (unsigned short*)(ws + off_w + 196608);
    float* F = (float*)(ws + off_w + 262144);
    float* stats0 = F;           // [512]
    float* stats1 = F + 512;     // [256]

    cvt_w_kernel<<<384, 256, 0, stream>>>(W0, W1, kxyz, wa, wb, wb1, kpack, F);
    nn_cand_kernel<<<2048, 256, 0, stream>>>(uxyz, kpack, cand);
    zgemm_kernel<<<256, 512, 0, stream>>>(kpts, wb, Zb);
    merge_interp_z_kernel<<<1024, 256, 0, stream>>>(cand, kpack, uxyz, Zb, xz);
    gemm1z_kernel<<<1024, 512, 0, stream>>>(upts, wa, xz, y0, stats0);
    gemm2_kernel<<<512, 512, 0, stream>>>(y0, wb1, stats0, g0, beta0, y1, stats1);
    bn_out_kernel<<<2048, 256, 0, stream>>>(y1, stats1, g1, beta1, out);
}